// Round 1
// baseline (111.494 us; speedup 1.0000x reference)
//
#include <hip/hip_runtime.h>
#include <math.h>

#define V 128000
#define H 1024
#define H3 3072

// ws layout (float offsets)
#define GI_OFF 0                 // 3072
#define GH_OFF 3072              // 3072
#define ROWS_PER_BLK 16
#define NBLK3 (V / ROWS_PER_BLK) // 8000 blocks for logits kernel
#define PART_OFF 6144            // 2 * NBLK3 = 16000
#define RED_OFF (PART_OFF + 2 * NBLK3)  // 22144; total ws use ~88.6 KB

__device__ __forceinline__ float wave_reduce_sum(float v) {
#pragma unroll
    for (int off = 32; off > 0; off >>= 1)
        v += __shfl_xor(v, off, 64);
    return v;
}

// Kernel 1: gi[j] = dot(w_ih[j], x) + b_ih[j];  gh[j] = dot(w_hh[j], h) + b_hh[j]
// One 64-lane wave per row; 4 waves/block; 2*3072 rows total.
__global__ __launch_bounds__(256) void k_gates(
    const int* __restrict__ token_p, const float* __restrict__ hidden,
    const float* __restrict__ emb,
    const float* __restrict__ w_ih, const float* __restrict__ w_hh,
    const float* __restrict__ b_ih, const float* __restrict__ b_hh,
    float* __restrict__ ws)
{
    const int gwave = (int)((blockIdx.x * blockDim.x + threadIdx.x) >> 6);
    const int lane  = threadIdx.x & 63;
    if (gwave >= 2 * H3) return;

    const float* w;
    const float* vec;
    float bias;
    float* out;
    if (gwave < H3) {
        const int row = gwave;
        w    = w_ih + (size_t)row * H;
        vec  = emb + (size_t)token_p[0] * H;   // low 32 bits correct for i32/i64 LE
        bias = b_ih[row];
        out  = ws + GI_OFF + row;
    } else {
        const int row = gwave - H3;
        w    = w_hh + (size_t)row * H;
        vec  = hidden;
        bias = b_hh[row];
        out  = ws + GH_OFF + row;
    }

    const float4* w4 = (const float4*)w;
    const float4* v4 = (const float4*)vec;
    float acc = 0.f;
#pragma unroll
    for (int it = 0; it < 4; ++it) {
        float4 a = w4[it * 64 + lane];
        float4 b = v4[it * 64 + lane];
        acc = fmaf(a.x, b.x, acc);
        acc = fmaf(a.y, b.y, acc);
        acc = fmaf(a.z, b.z, acc);
        acc = fmaf(a.w, b.w, acc);
    }
    acc = wave_reduce_sum(acc);
    if (lane == 0) *out = acc + bias;
}

// Kernel 2: gates -> h_new, written to d_out[V .. V+H)
__global__ __launch_bounds__(256) void k_combine(
    const float* __restrict__ hidden, const float* __restrict__ ws,
    float* __restrict__ d_out)
{
    const int k = blockIdx.x * blockDim.x + threadIdx.x;
    if (k >= H) return;
    const float gr = ws[GI_OFF + k]         + ws[GH_OFF + k];
    const float gz = ws[GI_OFF + H + k]     + ws[GH_OFF + H + k];
    const float gin = ws[GI_OFF + 2 * H + k];
    const float ghn = ws[GH_OFF + 2 * H + k];
    const float r = 1.f / (1.f + expf(-gr));
    const float z = 1.f / (1.f + expf(-gz));
    const float n = tanhf(gin + r * ghn);
    d_out[V + k] = (1.f - z) * n + z * hidden[k];
}

// Kernel 3: logits[row] = dot(w_out[row], h_new) + b_out[row]
// 4 waves/block, 4 rows/wave -> 16 rows/block, 8000 blocks.
// Also emits per-block (max, sumexp) partials for log_softmax.
__global__ __launch_bounds__(256) void k_logits(
    const float* __restrict__ w_out, const float* __restrict__ b_out,
    float* __restrict__ d_out, float* __restrict__ ws)
{
    __shared__ float sl[ROWS_PER_BLK];
    const int wave = threadIdx.x >> 6;
    const int lane = threadIdx.x & 63;

    // preload h_new (4 KB, hot in cache) into registers, reused across rows
    const float4* h4p = (const float4*)(d_out + V);
    float4 h4[4];
#pragma unroll
    for (int it = 0; it < 4; ++it) h4[it] = h4p[it * 64 + lane];

    const int base_row = blockIdx.x * ROWS_PER_BLK + wave * 4;
#pragma unroll
    for (int i = 0; i < 4; ++i) {
        const int row = base_row + i;
        const float4* w4 = (const float4*)(w_out + (size_t)row * H);
        float acc = 0.f;
#pragma unroll
        for (int it = 0; it < 4; ++it) {
            float4 a = w4[it * 64 + lane];
            acc = fmaf(a.x, h4[it].x, acc);
            acc = fmaf(a.y, h4[it].y, acc);
            acc = fmaf(a.z, h4[it].z, acc);
            acc = fmaf(a.w, h4[it].w, acc);
        }
        acc = wave_reduce_sum(acc);
        if (lane == 0) {
            const float l = acc + b_out[row];
            d_out[row] = l;
            sl[wave * 4 + i] = l;
        }
    }
    __syncthreads();
    if (threadIdx.x == 0) {
        float m = sl[0];
#pragma unroll
        for (int i = 1; i < ROWS_PER_BLK; ++i) m = fmaxf(m, sl[i]);
        float s = 0.f;
#pragma unroll
        for (int i = 0; i < ROWS_PER_BLK; ++i) s += expf(sl[i] - m);
        ws[PART_OFF + 2 * blockIdx.x]     = m;
        ws[PART_OFF + 2 * blockIdx.x + 1] = s;
    }
}

// Kernel 4: merge 8000 (max,sumexp) partials -> C = M + log(S)
__global__ __launch_bounds__(1024) void k_reduce(float* __restrict__ ws)
{
    __shared__ float sm[1024], ss[1024];
    const int t = threadIdx.x;
    float m = -INFINITY, s = 0.f;
    for (int i = t; i < NBLK3; i += 1024) {
        const float m2 = ws[PART_OFF + 2 * i];
        const float s2 = ws[PART_OFF + 2 * i + 1];
        if (m2 > m) { s = s * expf(m - m2) + s2; m = m2; }
        else        { s += s2 * expf(m2 - m); }
    }
    sm[t] = m; ss[t] = s;
    __syncthreads();
    for (int off = 512; off > 0; off >>= 1) {
        if (t < off) {
            float m2 = sm[t + off], s2 = ss[t + off];
            float mm = sm[t],       sc = ss[t];
            if (m2 > mm) { sc = sc * expf(mm - m2) + s2; mm = m2; }
            else         { sc += s2 * expf(m2 - mm); }
            sm[t] = mm; ss[t] = sc;
        }
        __syncthreads();
    }
    if (t == 0) ws[RED_OFF] = sm[0] + logf(ss[0]);
}

// Kernel 5: log_probs[i] = logits[i] - C, in place
__global__ __launch_bounds__(256) void k_final(
    float* __restrict__ d_out, const float* __restrict__ ws)
{
    const int i = blockIdx.x * blockDim.x + threadIdx.x;
    if (i < V) d_out[i] -= ws[RED_OFF];
}

extern "C" void kernel_launch(void* const* d_in, const int* in_sizes, int n_in,
                              void* d_out_v, int out_size, void* d_ws, size_t ws_size,
                              hipStream_t stream) {
    const int*   token  = (const int*)d_in[0];
    const float* hidden = (const float*)d_in[1];
    const float* emb    = (const float*)d_in[2];
    const float* w_ih   = (const float*)d_in[3];
    const float* w_hh   = (const float*)d_in[4];
    const float* b_ih   = (const float*)d_in[5];
    const float* b_hh   = (const float*)d_in[6];
    const float* w_out  = (const float*)d_in[7];
    const float* b_out  = (const float*)d_in[8];
    float* d_out = (float*)d_out_v;
    float* ws    = (float*)d_ws;

    k_gates  <<<(2 * H3) / 4, 256, 0, stream>>>(token, hidden, emb, w_ih, w_hh, b_ih, b_hh, ws);
    k_combine<<<(H + 255) / 256, 256, 0, stream>>>(hidden, ws, d_out);
    k_logits <<<NBLK3, 256, 0, stream>>>(w_out, b_out, d_out, ws);
    k_reduce <<<1, 1024, 0, stream>>>(ws);
    k_final  <<<(V + 255) / 256, 256, 0, stream>>>(d_out, ws);
}

// Round 2
// 98.936 us; speedup vs baseline: 1.1269x; 1.1269x over previous
//
#include <hip/hip_runtime.h>
#include <math.h>

#define V 128000
#define H 1024
#define H3 3072

typedef float f32x4 __attribute__((ext_vector_type(4)));

// ws layout (float offsets)
#define GI_OFF 0                 // 3072
#define GH_OFF 3072              // 3072
#define ROWS_PER_BLK 16
#define NBLK3 (V / ROWS_PER_BLK) // 8000 blocks for logits kernel
#define PART_OFF 6144            // 2 * NBLK3 = 16000
#define RED_OFF (PART_OFF + 2 * NBLK3)  // 22144

// Rows [0, R_CACHED) of w_out use normal (cacheable) loads -> become
// Infinity-Cache(L3)-resident across graph replays (196.6 MB < 256 MiB L3).
// Rows [R_CACHED, V) use non-temporal loads -> stream from HBM without
// evicting the resident head. 48000 * 4 KB = 196.6 MB; + w_ih/w_hh 25 MB.
#define R_CACHED 48000

__device__ __forceinline__ float wave_reduce_sum(float v) {
#pragma unroll
    for (int off = 32; off > 0; off >>= 1)
        v += __shfl_xor(v, off, 64);
    return v;
}

// Kernel 1: gi[j] = dot(w_ih[j], x) + b_ih[j];  gh[j] = dot(w_hh[j], h) + b_hh[j]
__global__ __launch_bounds__(256) void k_gates(
    const int* __restrict__ token_p, const float* __restrict__ hidden,
    const float* __restrict__ emb,
    const float* __restrict__ w_ih, const float* __restrict__ w_hh,
    const float* __restrict__ b_ih, const float* __restrict__ b_hh,
    float* __restrict__ ws)
{
    const int gwave = (int)((blockIdx.x * blockDim.x + threadIdx.x) >> 6);
    const int lane  = threadIdx.x & 63;
    if (gwave >= 2 * H3) return;

    const float* w;
    const float* vec;
    float bias;
    float* out;
    if (gwave < H3) {
        const int row = gwave;
        w    = w_ih + (size_t)row * H;
        vec  = emb + (size_t)token_p[0] * H;   // low 32 bits fine for i32/i64 LE
        bias = b_ih[row];
        out  = ws + GI_OFF + row;
    } else {
        const int row = gwave - H3;
        w    = w_hh + (size_t)row * H;
        vec  = hidden;
        bias = b_hh[row];
        out  = ws + GH_OFF + row;
    }

    const f32x4* w4 = (const f32x4*)w;
    const f32x4* v4 = (const f32x4*)vec;
    float acc = 0.f;
#pragma unroll
    for (int it = 0; it < 4; ++it) {
        f32x4 a = w4[it * 64 + lane];
        f32x4 b = v4[it * 64 + lane];
        acc = fmaf(a.x, b.x, acc);
        acc = fmaf(a.y, b.y, acc);
        acc = fmaf(a.z, b.z, acc);
        acc = fmaf(a.w, b.w, acc);
    }
    acc = wave_reduce_sum(acc);
    if (lane == 0) *out = acc + bias;
}

// Kernel 2: gates -> h_new, written to d_out[V .. V+H)
__global__ __launch_bounds__(256) void k_combine(
    const float* __restrict__ hidden, const float* __restrict__ ws,
    float* __restrict__ d_out)
{
    const int k = blockIdx.x * blockDim.x + threadIdx.x;
    if (k >= H) return;
    const float gr  = ws[GI_OFF + k]         + ws[GH_OFF + k];
    const float gz  = ws[GI_OFF + H + k]     + ws[GH_OFF + H + k];
    const float gin = ws[GI_OFF + 2 * H + k];
    const float ghn = ws[GH_OFF + 2 * H + k];
    const float r = 1.f / (1.f + expf(-gr));
    const float z = 1.f / (1.f + expf(-gz));
    const float n = tanhf(gin + r * ghn);
    d_out[V + k] = (1.f - z) * n + z * hidden[k];
}

// Kernel 3: logits[row] = dot(w_out[row], h_new) + b_out[row]
// 4 waves/block, 4 rows/wave; rows < R_CACHED cacheable, rest non-temporal.
__global__ __launch_bounds__(256) void k_logits(
    const float* __restrict__ w_out, const float* __restrict__ b_out,
    float* __restrict__ d_out, float* __restrict__ ws)
{
    __shared__ float sl[ROWS_PER_BLK];
    const int wave = threadIdx.x >> 6;
    const int lane = threadIdx.x & 63;

    // preload h_new (4 KB, L2-hot) into registers, reused across rows
    const f32x4* h4p = (const f32x4*)(d_out + V);
    f32x4 h4[4];
#pragma unroll
    for (int it = 0; it < 4; ++it) h4[it] = h4p[it * 64 + lane];

    const int base_row = blockIdx.x * ROWS_PER_BLK + wave * 4;
    float acc[4] = {0.f, 0.f, 0.f, 0.f};

    if (base_row + 3 < R_CACHED) {
#pragma unroll
        for (int i = 0; i < 4; ++i) {
            const f32x4* w4 = (const f32x4*)(w_out + (size_t)(base_row + i) * H);
#pragma unroll
            for (int it = 0; it < 4; ++it) {
                f32x4 a = w4[it * 64 + lane];
                acc[i] = fmaf(a.x, h4[it].x, acc[i]);
                acc[i] = fmaf(a.y, h4[it].y, acc[i]);
                acc[i] = fmaf(a.z, h4[it].z, acc[i]);
                acc[i] = fmaf(a.w, h4[it].w, acc[i]);
            }
        }
    } else {
#pragma unroll
        for (int i = 0; i < 4; ++i) {
            const f32x4* w4 = (const f32x4*)(w_out + (size_t)(base_row + i) * H);
#pragma unroll
            for (int it = 0; it < 4; ++it) {
                f32x4 a = __builtin_nontemporal_load(w4 + it * 64 + lane);
                acc[i] = fmaf(a.x, h4[it].x, acc[i]);
                acc[i] = fmaf(a.y, h4[it].y, acc[i]);
                acc[i] = fmaf(a.z, h4[it].z, acc[i]);
                acc[i] = fmaf(a.w, h4[it].w, acc[i]);
            }
        }
    }

#pragma unroll
    for (int i = 0; i < 4; ++i) {
        const float r = wave_reduce_sum(acc[i]);
        if (lane == 0) {
            const float l = r + b_out[base_row + i];
            d_out[base_row + i] = l;
            sl[wave * 4 + i] = l;
        }
    }
    __syncthreads();
    if (threadIdx.x == 0) {
        float m = sl[0];
#pragma unroll
        for (int i = 1; i < ROWS_PER_BLK; ++i) m = fmaxf(m, sl[i]);
        float s = 0.f;
#pragma unroll
        for (int i = 0; i < ROWS_PER_BLK; ++i) s += expf(sl[i] - m);
        ws[PART_OFF + 2 * blockIdx.x]     = m;
        ws[PART_OFF + 2 * blockIdx.x + 1] = s;
    }
}

// Kernel 4: merge 8000 (max,sumexp) partials -> C = M + log(S)
__global__ __launch_bounds__(1024) void k_reduce(float* __restrict__ ws)
{
    __shared__ float sm[1024], ss[1024];
    const int t = threadIdx.x;
    float m = -INFINITY, s = 0.f;
    for (int i = t; i < NBLK3; i += 1024) {
        const float m2 = ws[PART_OFF + 2 * i];
        const float s2 = ws[PART_OFF + 2 * i + 1];
        if (m2 > m) { s = s * expf(m - m2) + s2; m = m2; }
        else        { s += s2 * expf(m2 - m); }
    }
    sm[t] = m; ss[t] = s;
    __syncthreads();
    for (int off = 512; off > 0; off >>= 1) {
        if (t < off) {
            float m2 = sm[t + off], s2 = ss[t + off];
            float mm = sm[t],       sc = ss[t];
            if (m2 > mm) { sc = sc * expf(mm - m2) + s2; mm = m2; }
            else         { sc += s2 * expf(m2 - mm); }
            sm[t] = mm; ss[t] = sc;
        }
        __syncthreads();
    }
    if (t == 0) ws[RED_OFF] = sm[0] + logf(ss[0]);
}

// Kernel 5: log_probs[i] = logits[i] - C, in place
__global__ __launch_bounds__(256) void k_final(
    float* __restrict__ d_out, const float* __restrict__ ws)
{
    const int i = blockIdx.x * blockDim.x + threadIdx.x;
    if (i < V) d_out[i] -= ws[RED_OFF];
}

extern "C" void kernel_launch(void* const* d_in, const int* in_sizes, int n_in,
                              void* d_out_v, int out_size, void* d_ws, size_t ws_size,
                              hipStream_t stream) {
    const int*   token  = (const int*)d_in[0];
    const float* hidden = (const float*)d_in[1];
    const float* emb    = (const float*)d_in[2];
    const float* w_ih   = (const float*)d_in[3];
    const float* w_hh   = (const float*)d_in[4];
    const float* b_ih   = (const float*)d_in[5];
    const float* b_hh   = (const float*)d_in[6];
    const float* w_out  = (const float*)d_in[7];
    const float* b_out  = (const float*)d_in[8];
    float* d_out = (float*)d_out_v;
    float* ws    = (float*)d_ws;

    k_gates  <<<(2 * H3) / 4, 256, 0, stream>>>(token, hidden, emb, w_ih, w_hh, b_ih, b_hh, ws);
    k_combine<<<(H + 255) / 256, 256, 0, stream>>>(hidden, ws, d_out);
    k_logits <<<NBLK3, 256, 0, stream>>>(w_out, b_out, d_out, ws);
    k_reduce <<<1, 1024, 0, stream>>>(ws);
    k_final  <<<(V + 255) / 256, 256, 0, stream>>>(d_out, ws);
}